// Round 1
// baseline (157.490 us; speedup 1.0000x reference)
//
#include <hip/hip_runtime.h>

#define NN 8192
#define FLT_MAX_C 3.402823466e+38f

// Pass 1: deg[i] = w[i] + sum_j A[i][j]; store dinv[i] = rsqrt(deg[i]).
// One 256-thread block per row. Coalesced float4 loads: thread t reads
// vec-index t + k*256 (k = 0..7) -> 256*4*8 = 8192 floats = one row.
__global__ void __launch_bounds__(256)
row_rsqrt_kernel(const float* __restrict__ A,
                 const float* __restrict__ w,
                 float* __restrict__ dinv) {
    const int row = blockIdx.x;
    const float4* arow = reinterpret_cast<const float4*>(A + (size_t)row * NN);
    const int t = threadIdx.x;

    float s = 0.f;
#pragma unroll
    for (int k = 0; k < 8; ++k) {
        float4 v = arow[t + k * 256];
        s += (v.x + v.y) + (v.z + v.w);
    }

    // wave-64 butterfly reduce
#pragma unroll
    for (int off = 32; off > 0; off >>= 1)
        s += __shfl_down(s, off, 64);

    __shared__ float ws[4];
    const int lane = t & 63;
    const int wid = t >> 6;
    if (lane == 0) ws[wid] = s;
    __syncthreads();
    if (t == 0) {
        float deg = (ws[0] + ws[1]) + (ws[2] + ws[3]) + w[row];
        dinv[row] = rsqrtf(deg);
    }
}

// Pass 2: out[i][j] = (i==j ? 1 : 0) - (A[i][j] + (i==j)*w[i]) * dinv[i]*dinv[j]
// with nan_to_num semantics (NaN->0, +inf->FLT_MAX, -inf->-FLT_MAX).
// Grid-stride, 4 elements (float4) per thread, fully coalesced.
__global__ void __launch_bounds__(256)
laplacian_kernel(const float* __restrict__ A,
                 const float* __restrict__ w,
                 const float* __restrict__ dinv,
                 float* __restrict__ out) {
    const size_t total_vec = (size_t)NN * NN / 4;
    const size_t stride = (size_t)gridDim.x * blockDim.x;

    for (size_t idx = (size_t)blockIdx.x * blockDim.x + threadIdx.x;
         idx < total_vec; idx += stride) {
        const size_t base = idx * 4;
        const int i = (int)(base >> 13);      // N = 8192 = 2^13
        const int j0 = (int)(base & (NN - 1));

        float4 a = *reinterpret_cast<const float4*>(A + base);
        float4 dj = *reinterpret_cast<const float4*>(dinv + j0);
        const float di = dinv[i];

        float av[4] = {a.x, a.y, a.z, a.w};
        float djv[4] = {dj.x, dj.y, dj.z, dj.w};
        float o[4];
#pragma unroll
        for (int k = 0; k < 4; ++k) {
            const int j = j0 + k;
            float aij = av[k];
            float eye = 0.f;
            if (j == i) {            // diagonal: add self-loop weight, identity term
                aij += w[i];
                eye = 1.f;
            }
            float v = eye - aij * di * djv[k];
            // nan_to_num: NaN -> 0, +/-inf -> +/-FLT_MAX
            v = (v != v) ? 0.f : fminf(fmaxf(v, -FLT_MAX_C), FLT_MAX_C);
            o[k] = v;
        }
        float4 ov = make_float4(o[0], o[1], o[2], o[3]);
        *reinterpret_cast<float4*>(out + base) = ov;
    }
}

extern "C" void kernel_launch(void* const* d_in, const int* in_sizes, int n_in,
                              void* d_out, int out_size, void* d_ws, size_t ws_size,
                              hipStream_t stream) {
    const float* A = (const float*)d_in[0];    // [N*N] fp32
    const float* w = (const float*)d_in[1];    // [N]   fp32
    float* out = (float*)d_out;                // [N*N] fp32
    float* dinv = (float*)d_ws;                // [N]   fp32 scratch

    row_rsqrt_kernel<<<NN, 256, 0, stream>>>(A, w, dinv);
    laplacian_kernel<<<2048, 256, 0, stream>>>(A, w, dinv, out);
}

// Round 3
// 125.875 us; speedup vs baseline: 1.2512x; 1.2512x over previous
//
#include <hip/hip_runtime.h>

#define NN 8192
#define FLT_MAX_C 3.402823466e+38f

typedef float f32x4 __attribute__((ext_vector_type(4)));

// Pass 1: deg[i] = w[i] + sum_j A[i][j]; store dinv[i] = rsqrt(deg[i]).
// One 256-thread block per row. Coalesced float4 loads: thread t reads
// vec-index t + k*256 (k = 0..7) -> 256*4*8 = 8192 floats = one row.
// Normal (caching) loads on purpose: this pass populates L3 with A.
__global__ void __launch_bounds__(256)
row_rsqrt_kernel(const float* __restrict__ A,
                 const float* __restrict__ w,
                 float* __restrict__ dinv) {
    const int row = blockIdx.x;
    const f32x4* arow = reinterpret_cast<const f32x4*>(A + (size_t)row * NN);
    const int t = threadIdx.x;

    float s = 0.f;
#pragma unroll
    for (int k = 0; k < 8; ++k) {
        f32x4 v = arow[t + k * 256];
        s += (v.x + v.y) + (v.z + v.w);
    }

    // wave-64 butterfly reduce
#pragma unroll
    for (int off = 32; off > 0; off >>= 1)
        s += __shfl_down(s, off, 64);

    __shared__ float ws[4];
    const int lane = t & 63;
    const int wid = t >> 6;
    if (lane == 0) ws[wid] = s;
    __syncthreads();
    if (t == 0) {
        float deg = (ws[0] + ws[1]) + (ws[2] + ws[3]) + w[row];
        dinv[row] = rsqrtf(deg);
    }
}

// Pass 2: out[i][j] = (i==j ? 1 : 0) - (A[i][j] + (i==j)*w[i]) * dinv[i]*dinv[j]
// with nan_to_num semantics (NaN->0, +/-inf -> +/-FLT_MAX).
// Grid-stride, float4 per thread, fully coalesced.
// KEY: output stores are NONTEMPORAL so they don't evict A from the 256 MiB
// Infinity Cache -- pass 1 just streamed all 256 MiB of A through L3, and
// this pass re-reads it; keeping A resident makes this pass write-bound.
__global__ void __launch_bounds__(256)
laplacian_kernel(const float* __restrict__ A,
                 const float* __restrict__ w,
                 const float* __restrict__ dinv,
                 float* __restrict__ out) {
    const size_t total_vec = (size_t)NN * NN / 4;
    const size_t stride = (size_t)gridDim.x * blockDim.x;

    for (size_t idx = (size_t)blockIdx.x * blockDim.x + threadIdx.x;
         idx < total_vec; idx += stride) {
        const size_t base = idx * 4;
        const int i = (int)(base >> 13);      // N = 8192 = 2^13
        const int j0 = (int)(base & (NN - 1));

        f32x4 a = *reinterpret_cast<const f32x4*>(A + base);
        f32x4 dj = *reinterpret_cast<const f32x4*>(dinv + j0);
        const float di = dinv[i];

        f32x4 o;
#pragma unroll
        for (int k = 0; k < 4; ++k) {
            const int j = j0 + k;
            float aij = a[k];
            float eye = 0.f;
            if (j == i) {            // diagonal: add self-loop weight, identity term
                aij += w[i];
                eye = 1.f;
            }
            float v = eye - aij * di * dj[k];
            // nan_to_num: NaN -> 0, +/-inf -> +/-FLT_MAX
            v = (v != v) ? 0.f : fminf(fmaxf(v, -FLT_MAX_C), FLT_MAX_C);
            o[k] = v;
        }
        __builtin_nontemporal_store(o, reinterpret_cast<f32x4*>(out + base));
    }
}

extern "C" void kernel_launch(void* const* d_in, const int* in_sizes, int n_in,
                              void* d_out, int out_size, void* d_ws, size_t ws_size,
                              hipStream_t stream) {
    const float* A = (const float*)d_in[0];    // [N*N] fp32
    const float* w = (const float*)d_in[1];    // [N]   fp32
    float* out = (float*)d_out;                // [N*N] fp32
    float* dinv = (float*)d_ws;                // [N]   fp32 scratch

    row_rsqrt_kernel<<<NN, 256, 0, stream>>>(A, w, dinv);
    laplacian_kernel<<<2048, 256, 0, stream>>>(A, w, dinv, out);
}